// Round 9
// baseline (76.025 us; speedup 1.0000x reference)
//
#include <hip/hip_runtime.h>

#define T_STEPS 32768
#define NROWS 188
#define NWAVES 12      // ceil(188 / 16 rows-per-wave)
#define SEGS 256       // parallel-in-time segments (3 waves/SIMD; sweet spot per r2/r7/r8 calibration)
#define SEG_LEN (T_STEPS / SEGS)   // 128
#define WARMUP 32      // washout; HW-certified in r8 (absmax identical to W=64)
#define UB 16          // unroll/batch width (divides WARMUP and SEG_LEN)

typedef float f2 __attribute__((ext_vector_type(2)));

__device__ __forceinline__ float fexp2(float x) { return __builtin_amdgcn_exp2f(x); }
__device__ __forceinline__ float frcp(float x) { return __builtin_amdgcn_rcpf(x); }

// Guaranteed-packed FMA: d = a*b + c elementwise on both f32 halves.
// ALL VOP3P-f32 operands must be 64-bit VGPR pairs (r5 lesson).
__device__ __forceinline__ f2 pk_fma(f2 a, f2 b, f2 c) {
  f2 d;
  asm("v_pk_fma_f32 %0, %1, %2, %3"
      : "=v"(d)
      : "v"(a), "v"(b), "v"(c));
  return d;
}

__device__ __forceinline__ f2 mkpair(float a) {
  f2 r = {a, a};
  return r;
}

// Broadcast lane (quad_base + J)'s value to all 4 lanes of the quad (DPP quad_perm).
template <int J>
__device__ __forceinline__ float qbcast(float v) {
  int i = __builtin_amdgcn_mov_dpp(__builtin_bit_cast(int, v), J * 0x55, 0xF, 0xF, true);
  return __builtin_bit_cast(float, i);
}

// 128-thread block = 2 independent waves (no barriers). Wave wv handles time
// segment s = blockIdx.y*2 + wv; lane l = r*4+g handles row n = blockIdx.x*16+r,
// hidden cell g. pa = (yf, yi) scaled S1; pb = (yc scaled S2, yo scaled S1).
// With A=2^pa.x, B=2^pa.y, Ec=2^pb.x, C=2^pb.y:
//   cn = [c*(1+B)(1+Ec) + (1-Ec)(1+A)] / [(1+A)(1+B)(1+Ec)]    (1 rcp for 3)
//   E = 2^(S2*cn):  h = (1-E)/((1+E)(1+C)),  o = (1+E)*same_rcp (1 rcp for 2)
// c-state carried S2-scaled. 7 transcendentals/step.
// Segment s emits t in [s*SEG_LEN, (s+1)*SEG_LEN) after washout from
// t0 = max(0, s*SEG_LEN - WARMUP) at zero state (segment 0: true h0/c0).
template <bool USE_WS>
__global__ __launch_bounds__(128) void lstm_scan_kernel(
    const float* __restrict__ x, const float* __restrict__ h0v,
    const float* __restrict__ c0v, const float* __restrict__ Wf,
    const float* __restrict__ bf, const float* __restrict__ Wi,
    const float* __restrict__ bi, const float* __restrict__ Wc,
    const float* __restrict__ bc, const float* __restrict__ Wo,
    const float* __restrict__ bo, const float* __restrict__ Ww,
    float* __restrict__ dst) {
  const int l = threadIdx.x & 63;
  const int wv = threadIdx.x >> 6;
  const int r = l >> 2;
  const int g = l & 3;
  int n = blockIdx.x * 16 + r;
  const bool valid = (n < NROWS);
  if (!valid) n = NROWS - 1;  // clamp: dummy lanes duplicate row 187, contribute 0

  const float S1 = -1.4426950408889634f;
  const float S2 = -2.8853900817779268f;

  // packed weights: .x = {f|c} member, .y = {i|o} member
  const f2 wa0 = {S1 * Wf[g * 5 + 0], S1 * Wi[g * 5 + 0]};
  const f2 wa1 = {S1 * Wf[g * 5 + 1], S1 * Wi[g * 5 + 1]};
  const f2 wa2 = {S1 * Wf[g * 5 + 2], S1 * Wi[g * 5 + 2]};
  const f2 wa3 = {S1 * Wf[g * 5 + 3], S1 * Wi[g * 5 + 3]};
  const f2 wa4 = {S1 * Wf[g * 5 + 4], S1 * Wi[g * 5 + 4]};
  const f2 ba  = {S1 * bf[g],          S1 * bi[g]};
  const f2 wb0 = {S2 * Wc[g * 5 + 0], S1 * Wo[g * 5 + 0]};
  const f2 wb1 = {S2 * Wc[g * 5 + 1], S1 * Wo[g * 5 + 1]};
  const f2 wb2 = {S2 * Wc[g * 5 + 2], S1 * Wo[g * 5 + 2]};
  const f2 wb3 = {S2 * Wc[g * 5 + 3], S1 * Wo[g * 5 + 3]};
  const f2 wb4 = {S2 * Wc[g * 5 + 4], S1 * Wo[g * 5 + 4]};
  const f2 bb  = {S2 * bc[g],          S1 * bo[g]};
  const float wwn = valid ? Ww[n] : 0.0f;

  const int s = blockIdx.y * 2 + wv;
  const int seg_start = s * SEG_LEN;
  int t0 = seg_start - WARMUP;
  if (t0 < 0) t0 = 0;

  float h, cp;
  if (s == 0) {
    h = h0v[n * 4 + g];
    cp = S2 * c0v[n * 4 + g];
  } else {
    h = 0.0f;
    cp = 0.0f;
  }

  float* pt = nullptr;
  if constexpr (USE_WS) pt = dst + (size_t)blockIdx.x * T_STEPS * 4;

  // one recurrence step; returns o_ (output gate; DCE'd in warmup)
  auto step = [&](float xv) -> float {
    const f2 xp = mkpair(xv);
    f2 pa = pk_fma(xp, wa0, ba);
    f2 pb = pk_fma(xp, wb0, bb);
    const f2 h0p = mkpair(qbcast<0>(h));
    const f2 h1p = mkpair(qbcast<1>(h));
    const f2 h2p = mkpair(qbcast<2>(h));
    const f2 h3p = mkpair(qbcast<3>(h));
    pa = pk_fma(h0p, wa1, pa);  pb = pk_fma(h0p, wb1, pb);
    pa = pk_fma(h1p, wa2, pa);  pb = pk_fma(h1p, wb2, pb);
    pa = pk_fma(h2p, wa3, pa);  pb = pk_fma(h2p, wb3, pb);
    pa = pk_fma(h3p, wa4, pa);  pb = pk_fma(h3p, wb4, pb);
    const float A  = fexp2(pa.x);
    const float B  = fexp2(pa.y);
    const float Ec = fexp2(pb.x);
    const float C  = fexp2(pb.y);
    const float oA  = 1.0f + A;
    const float oB  = 1.0f + B;
    const float oEc = 1.0f + Ec;
    const float oC  = 1.0f + C;
    const float t1 = oB * oEc;
    const float t2 = fmaf(-S2, Ec, S2) * oA;   // S2*(1-Ec)*(1+A)
    const float num = fmaf(cp, t1, t2);
    const float rD = frcp(t1 * oA);
    cp = fminf(num * rD, 60.0f);               // S2*cn; clamp: keep 2^cp finite
    const float E = fexp2(cp);
    const float oE = 1.0f + E;
    const float rT = frcp(oE * oC);
    h = (1.0f - E) * rT;                       // tanh(cn) * o
    return oE * rT;                            // o
  };

  float xa[UB], xb[UB];
#pragma unroll
  for (int u = 0; u < UB; ++u) xa[u] = x[(t0 + u) * NROWS + n];

  // ---- warmup (washout): no output; prefetch stays < seg_start+UB <= T ----
  for (int t = t0; t < seg_start; t += UB) {
#pragma unroll
    for (int u = 0; u < UB; ++u) xb[u] = x[(t + UB + u) * NROWS + n];
#pragma unroll
    for (int u = 0; u < UB; ++u) (void)step(xa[u]);
#pragma unroll
    for (int u = 0; u < UB; ++u) xa[u] = xb[u];
  }

  // ---- main segment: batch UB steps, then batched cross-lane reduce ----
  for (int t = seg_start; t < seg_start + SEG_LEN; t += UB) {
#pragma unroll
    for (int u = 0; u < UB; ++u) {
      int tp = t + UB + u;                    // uniform -> scalar cmp/select
      if (tp > T_STEPS - 1) tp = T_STEPS - 1;
      xb[u] = x[tp * NROWS + n];
    }
    float ov[UB];
#pragma unroll
    for (int u = 0; u < UB; ++u) ov[u] = step(xa[u]);
#pragma unroll
    for (int u = 0; u < UB; ++u) ov[u] *= wwn;
#pragma unroll
    for (int u = 0; u < UB; ++u) ov[u] += __shfl_xor(ov[u], 4);
#pragma unroll
    for (int u = 0; u < UB; ++u) ov[u] += __shfl_xor(ov[u], 8);
#pragma unroll
    for (int u = 0; u < UB; ++u) ov[u] += __shfl_xor(ov[u], 16);
#pragma unroll
    for (int u = 0; u < UB; ++u) ov[u] += __shfl_xor(ov[u], 32);
    if constexpr (USE_WS) {
      if (l < 4) {
#pragma unroll
        for (int u = 0; u < UB; ++u) pt[(t + u) * 4 + l] = ov[u];
      }
    } else {
      if (l < 4) {
#pragma unroll
        for (int u = 0; u < UB; ++u) atomicAdd(&dst[(t + u) * 4 + l], ov[u]);
      }
    }
#pragma unroll
    for (int u = 0; u < UB; ++u) xa[u] = xb[u];
  }
}

__global__ __launch_bounds__(256) void reduce_out_kernel(
    const float* __restrict__ partial, const float* __restrict__ bwp,
    float* __restrict__ out) {
  const int idx = blockIdx.x * 256 + threadIdx.x;
  if (idx >= T_STEPS * 4) return;
  float s = bwp[0];
#pragma unroll
  for (int w = 0; w < NWAVES; ++w) s += partial[(size_t)w * T_STEPS * 4 + idx];
  out[idx] = s;
}

__global__ __launch_bounds__(256) void init_out_kernel(
    const float* __restrict__ bwp, float* __restrict__ out) {
  const int idx = blockIdx.x * 256 + threadIdx.x;
  if (idx < T_STEPS * 4) out[idx] = bwp[0];
}

extern "C" void kernel_launch(void* const* d_in, const int* in_sizes, int n_in,
                              void* d_out, int out_size, void* d_ws, size_t ws_size,
                              hipStream_t stream) {
  const float* x  = (const float*)d_in[0];
  const float* h0 = (const float*)d_in[1];
  const float* c0 = (const float*)d_in[2];
  const float* Wf = (const float*)d_in[3];
  const float* bf = (const float*)d_in[4];
  const float* Wi = (const float*)d_in[5];
  const float* bi = (const float*)d_in[6];
  const float* Wc = (const float*)d_in[7];
  const float* bc = (const float*)d_in[8];
  const float* Wo = (const float*)d_in[9];
  const float* bo = (const float*)d_in[10];
  const float* Ww = (const float*)d_in[11];
  const float* bw = (const float*)d_in[12];
  float* out = (float*)d_out;

  const size_t need = (size_t)NWAVES * T_STEPS * 4 * sizeof(float);
  const int nout_blocks = (T_STEPS * 4 + 255) / 256;
  const dim3 grid(NWAVES, SEGS / 2);
  if (ws_size >= need) {
    float* partial = (float*)d_ws;
    lstm_scan_kernel<true><<<grid, 128, 0, stream>>>(
        x, h0, c0, Wf, bf, Wi, bi, Wc, bc, Wo, bo, Ww, partial);
    reduce_out_kernel<<<nout_blocks, 256, 0, stream>>>(partial, bw, out);
  } else {
    init_out_kernel<<<nout_blocks, 256, 0, stream>>>(bw, out);
    lstm_scan_kernel<false><<<grid, 128, 0, stream>>>(
        x, h0, c0, Wf, bf, Wi, bi, Wc, bc, Wo, bo, Ww, out);
  }
}

// Round 10
// 61.830 us; speedup vs baseline: 1.2296x; 1.2296x over previous
//
#include <hip/hip_runtime.h>

#define T_STEPS 32768
#define NROWS 188
#define NWAVES 12      // ceil(188 / 16 rows-per-wave)
#define SEGS 256       // parallel-in-time segments
#define SEG_LEN (T_STEPS / SEGS)   // 128
#define WARMUP 32      // washout; HW-certified in r8/r9 (absmax at algebra floor)
#define UB 16          // unroll/batch width (divides WARMUP and SEG_LEN)

typedef float f2 __attribute__((ext_vector_type(2)));

__device__ __forceinline__ float fexp2(float x) { return __builtin_amdgcn_exp2f(x); }
__device__ __forceinline__ float frcp(float x) { return __builtin_amdgcn_rcpf(x); }

// Guaranteed-packed FMA: d = a*b + c elementwise on both f32 halves.
// ALL VOP3P-f32 operands must be 64-bit VGPR pairs (r5 lesson).
__device__ __forceinline__ f2 pk_fma(f2 a, f2 b, f2 c) {
  f2 d;
  asm("v_pk_fma_f32 %0, %1, %2, %3"
      : "=v"(d)
      : "v"(a), "v"(b), "v"(c));
  return d;
}

__device__ __forceinline__ f2 mkpair(float a) {
  f2 r = {a, a};
  return r;
}

// Broadcast lane (quad_base + J)'s value to all 4 lanes of the quad (DPP quad_perm).
template <int J>
__device__ __forceinline__ float qbcast(float v) {
  int i = __builtin_amdgcn_mov_dpp(__builtin_bit_cast(int, v), J * 0x55, 0xF, 0xF, true);
  return __builtin_bit_cast(float, i);
}

// ONE wave per workgroup (r9 lesson: multi-wave WGs place waves on SIMDs as a
// granule; with few WGs/CU this imbalances per-SIMD wave counts — {4,4,2,2}
// instead of {3,3,3,3} — and the stragglers set the wall clock).
// Lane l = r*4+g handles row n = blockIdx.x*16+r, hidden cell g; blockIdx.y = s.
// pa = (yf, yi) scaled S1; pb = (yc scaled S2, yo scaled S1).
// With A=2^pa.x, B=2^pa.y, Ec=2^pb.x, C=2^pb.y:
//   cn = [c*(1+B)(1+Ec) + (1-Ec)(1+A)] / [(1+A)(1+B)(1+Ec)]    (1 rcp for 3)
//   E = 2^(S2*cn):  h = (1-E)/((1+E)(1+C)),  o = (1+E)*same_rcp (1 rcp for 2)
// c-state carried S2-scaled. 7 transcendentals/step.
// Segment s emits t in [s*SEG_LEN, (s+1)*SEG_LEN) after washout from
// t0 = max(0, s*SEG_LEN - WARMUP) at zero state (segment 0: true h0/c0).
template <bool USE_WS>
__global__ __launch_bounds__(64) void lstm_scan_kernel(
    const float* __restrict__ x, const float* __restrict__ h0v,
    const float* __restrict__ c0v, const float* __restrict__ Wf,
    const float* __restrict__ bf, const float* __restrict__ Wi,
    const float* __restrict__ bi, const float* __restrict__ Wc,
    const float* __restrict__ bc, const float* __restrict__ Wo,
    const float* __restrict__ bo, const float* __restrict__ Ww,
    float* __restrict__ dst) {
  const int l = threadIdx.x;
  const int r = l >> 2;
  const int g = l & 3;
  int n = blockIdx.x * 16 + r;
  const bool valid = (n < NROWS);
  if (!valid) n = NROWS - 1;  // clamp: dummy lanes duplicate row 187, contribute 0

  const float S1 = -1.4426950408889634f;
  const float S2 = -2.8853900817779268f;

  // packed weights: .x = {f|c} member, .y = {i|o} member
  const f2 wa0 = {S1 * Wf[g * 5 + 0], S1 * Wi[g * 5 + 0]};
  const f2 wa1 = {S1 * Wf[g * 5 + 1], S1 * Wi[g * 5 + 1]};
  const f2 wa2 = {S1 * Wf[g * 5 + 2], S1 * Wi[g * 5 + 2]};
  const f2 wa3 = {S1 * Wf[g * 5 + 3], S1 * Wi[g * 5 + 3]};
  const f2 wa4 = {S1 * Wf[g * 5 + 4], S1 * Wi[g * 5 + 4]};
  const f2 ba  = {S1 * bf[g],          S1 * bi[g]};
  const f2 wb0 = {S2 * Wc[g * 5 + 0], S1 * Wo[g * 5 + 0]};
  const f2 wb1 = {S2 * Wc[g * 5 + 1], S1 * Wo[g * 5 + 1]};
  const f2 wb2 = {S2 * Wc[g * 5 + 2], S1 * Wo[g * 5 + 2]};
  const f2 wb3 = {S2 * Wc[g * 5 + 3], S1 * Wo[g * 5 + 3]};
  const f2 wb4 = {S2 * Wc[g * 5 + 4], S1 * Wo[g * 5 + 4]};
  const f2 bb  = {S2 * bc[g],          S1 * bo[g]};
  const float wwn = valid ? Ww[n] : 0.0f;

  const int s = blockIdx.y;
  const int seg_start = s * SEG_LEN;
  int t0 = seg_start - WARMUP;
  if (t0 < 0) t0 = 0;

  float h, cp;
  if (s == 0) {
    h = h0v[n * 4 + g];
    cp = S2 * c0v[n * 4 + g];
  } else {
    h = 0.0f;
    cp = 0.0f;
  }

  float* pt = nullptr;
  if constexpr (USE_WS) pt = dst + (size_t)blockIdx.x * T_STEPS * 4;

  // one recurrence step; returns o_ (output gate; DCE'd in warmup)
  auto step = [&](float xv) -> float {
    const f2 xp = mkpair(xv);
    f2 pa = pk_fma(xp, wa0, ba);
    f2 pb = pk_fma(xp, wb0, bb);
    const f2 h0p = mkpair(qbcast<0>(h));
    const f2 h1p = mkpair(qbcast<1>(h));
    const f2 h2p = mkpair(qbcast<2>(h));
    const f2 h3p = mkpair(qbcast<3>(h));
    pa = pk_fma(h0p, wa1, pa);  pb = pk_fma(h0p, wb1, pb);
    pa = pk_fma(h1p, wa2, pa);  pb = pk_fma(h1p, wb2, pb);
    pa = pk_fma(h2p, wa3, pa);  pb = pk_fma(h2p, wb3, pb);
    pa = pk_fma(h3p, wa4, pa);  pb = pk_fma(h3p, wb4, pb);
    const float A  = fexp2(pa.x);
    const float B  = fexp2(pa.y);
    const float Ec = fexp2(pb.x);
    const float C  = fexp2(pb.y);
    const float oA  = 1.0f + A;
    const float oB  = 1.0f + B;
    const float oEc = 1.0f + Ec;
    const float oC  = 1.0f + C;
    const float t1 = oB * oEc;
    const float t2 = fmaf(-S2, Ec, S2) * oA;   // S2*(1-Ec)*(1+A)
    const float num = fmaf(cp, t1, t2);
    const float rD = frcp(t1 * oA);
    cp = fminf(num * rD, 60.0f);               // S2*cn; clamp: keep 2^cp finite
    const float E = fexp2(cp);
    const float oE = 1.0f + E;
    const float rT = frcp(oE * oC);
    h = (1.0f - E) * rT;                       // tanh(cn) * o
    return oE * rT;                            // o
  };

  float xa[UB], xb[UB];
#pragma unroll
  for (int u = 0; u < UB; ++u) xa[u] = x[(t0 + u) * NROWS + n];

  // ---- warmup (washout): no output; prefetch stays < seg_start+UB <= T ----
  for (int t = t0; t < seg_start; t += UB) {
#pragma unroll
    for (int u = 0; u < UB; ++u) xb[u] = x[(t + UB + u) * NROWS + n];
#pragma unroll
    for (int u = 0; u < UB; ++u) (void)step(xa[u]);
#pragma unroll
    for (int u = 0; u < UB; ++u) xa[u] = xb[u];
  }

  // ---- main segment: batch UB steps, then batched cross-lane reduce ----
  for (int t = seg_start; t < seg_start + SEG_LEN; t += UB) {
#pragma unroll
    for (int u = 0; u < UB; ++u) {
      int tp = t + UB + u;                    // uniform -> scalar cmp/select
      if (tp > T_STEPS - 1) tp = T_STEPS - 1;
      xb[u] = x[tp * NROWS + n];
    }
    float ov[UB];
#pragma unroll
    for (int u = 0; u < UB; ++u) ov[u] = step(xa[u]);
#pragma unroll
    for (int u = 0; u < UB; ++u) ov[u] *= wwn;
#pragma unroll
    for (int u = 0; u < UB; ++u) ov[u] += __shfl_xor(ov[u], 4);
#pragma unroll
    for (int u = 0; u < UB; ++u) ov[u] += __shfl_xor(ov[u], 8);
#pragma unroll
    for (int u = 0; u < UB; ++u) ov[u] += __shfl_xor(ov[u], 16);
#pragma unroll
    for (int u = 0; u < UB; ++u) ov[u] += __shfl_xor(ov[u], 32);
    if constexpr (USE_WS) {
      if (l < 4) {
#pragma unroll
        for (int u = 0; u < UB; ++u) pt[(t + u) * 4 + l] = ov[u];
      }
    } else {
      if (l < 4) {
#pragma unroll
        for (int u = 0; u < UB; ++u) atomicAdd(&dst[(t + u) * 4 + l], ov[u]);
      }
    }
#pragma unroll
    for (int u = 0; u < UB; ++u) xa[u] = xb[u];
  }
}

__global__ __launch_bounds__(256) void reduce_out_kernel(
    const float* __restrict__ partial, const float* __restrict__ bwp,
    float* __restrict__ out) {
  const int idx = blockIdx.x * 256 + threadIdx.x;
  if (idx >= T_STEPS * 4) return;
  float s = bwp[0];
#pragma unroll
  for (int w = 0; w < NWAVES; ++w) s += partial[(size_t)w * T_STEPS * 4 + idx];
  out[idx] = s;
}

__global__ __launch_bounds__(256) void init_out_kernel(
    const float* __restrict__ bwp, float* __restrict__ out) {
  const int idx = blockIdx.x * 256 + threadIdx.x;
  if (idx < T_STEPS * 4) out[idx] = bwp[0];
}

extern "C" void kernel_launch(void* const* d_in, const int* in_sizes, int n_in,
                              void* d_out, int out_size, void* d_ws, size_t ws_size,
                              hipStream_t stream) {
  const float* x  = (const float*)d_in[0];
  const float* h0 = (const float*)d_in[1];
  const float* c0 = (const float*)d_in[2];
  const float* Wf = (const float*)d_in[3];
  const float* bf = (const float*)d_in[4];
  const float* Wi = (const float*)d_in[5];
  const float* bi = (const float*)d_in[6];
  const float* Wc = (const float*)d_in[7];
  const float* bc = (const float*)d_in[8];
  const float* Wo = (const float*)d_in[9];
  const float* bo = (const float*)d_in[10];
  const float* Ww = (const float*)d_in[11];
  const float* bw = (const float*)d_in[12];
  float* out = (float*)d_out;

  const size_t need = (size_t)NWAVES * T_STEPS * 4 * sizeof(float);
  const int nout_blocks = (T_STEPS * 4 + 255) / 256;
  const dim3 grid(NWAVES, SEGS);
  if (ws_size >= need) {
    float* partial = (float*)d_ws;
    lstm_scan_kernel<true><<<grid, 64, 0, stream>>>(
        x, h0, c0, Wf, bf, Wi, bi, Wc, bc, Wo, bo, Ww, partial);
    reduce_out_kernel<<<nout_blocks, 256, 0, stream>>>(partial, bw, out);
  } else {
    init_out_kernel<<<nout_blocks, 256, 0, stream>>>(bw, out);
    lstm_scan_kernel<false><<<grid, 64, 0, stream>>>(
        x, h0, c0, Wf, bf, Wi, bi, Wc, bc, Wo, bo, Ww, out);
  }
}